// Round 7
// baseline (433.573 us; speedup 1.0000x reference)
//
#include <hip/hip_runtime.h>
#include <stdint.h>

#define MDIM 16384
#define NDIM 8192
#define KDIM 2048
#define EPS32 1.1920928955078125e-07f
#define BM 256
#define BN 256
#define BK 64

using i32x4 = __attribute__((ext_vector_type(4))) int;
using i32x16 = __attribute__((ext_vector_type(16))) int;
using f32x4 = __attribute__((ext_vector_type(4))) float;
typedef __attribute__((address_space(3))) const int8_t* lds_cptr;

__device__ __forceinline__ void gload_lds16(const void* g, void* l) {
  __builtin_amdgcn_global_load_lds(
      (const __attribute__((address_space(1))) void*)g,
      (__attribute__((address_space(3))) void*)l,
      16, 0, 0);
}

__device__ __forceinline__ uint32_t sgnb(float v) { return (v < 0.f) ? 0xFFu : 0x01u; }

// ---------------------------------------------------------------------------
// Fused pack: blocks [0,MDIM) pack A rows + ab[m]; blocks [MDIM, MDIM+2048)
// pack B transposed tiles + atomicMax column bound.
// ---------------------------------------------------------------------------
__global__ __launch_bounds__(256) void k_pack(const float* __restrict__ x,
                                              const float* __restrict__ W,
                                              int8_t* __restrict__ As,
                                              int8_t* __restrict__ Bs,
                                              float* __restrict__ ab,
                                              unsigned int* __restrict__ wbu) {
  __shared__ char sm[64 * 68];
  __shared__ float red[4][64];
  const int t = threadIdx.x;
  if (blockIdx.x < MDIM) {
    const int m = blockIdx.x;
    const float4* row = (const float4*)(x + (size_t)m * KDIM);
    const float4 v0 = row[2 * t];
    const float4 v1 = row[2 * t + 1];
    const uint32_t p0 = sgnb(v0.x) | (sgnb(v0.y) << 8) | (sgnb(v0.z) << 16) | (sgnb(v0.w) << 24);
    const uint32_t p1 = sgnb(v1.x) | (sgnb(v1.y) << 8) | (sgnb(v1.z) << 16) | (sgnb(v1.w) << 24);
    ((uint2*)(As + (size_t)m * KDIM))[t] = make_uint2(p0, p1);
    float mx = fmaxf(fmaxf(fabsf(v0.x), fabsf(v0.y)), fmaxf(fabsf(v0.z), fabsf(v0.w)));
    mx = fmaxf(mx, fmaxf(fmaxf(fabsf(v1.x), fabsf(v1.y)), fmaxf(fabsf(v1.w), fabsf(v1.z))));
#pragma unroll
    for (int o = 32; o > 0; o >>= 1) mx = fmaxf(mx, __shfl_xor(mx, o, 64));
    if ((t & 63) == 0) red[0][t >> 6] = mx;
    __syncthreads();
    if (t == 0)
      ab[m] = fmaxf(fmaxf(red[0][0], red[0][1]), fmaxf(red[0][2], red[0][3])) + EPS32;
  } else {
    const int bid = blockIdx.x - MDIM;
    const int bd = bid & 31;  // 2048/64 d-tiles
    const int bf = bid >> 5;  // 8192/64 f-tiles
    const int d0 = bd * 64, f0 = bf * 64;
    const int fl = t & 63, dq = t >> 6;
    float mx = 0.f;
#pragma unroll
    for (int i = 0; i < 16; ++i) {
      const int dl = i * 4 + dq;
      const float v = W[(size_t)(d0 + dl) * NDIM + f0 + fl];
      sm[fl * 68 + dl] = (v < 0.f) ? (char)-1 : (char)1;
      mx = fmaxf(mx, fabsf(v));
    }
    red[dq][fl] = mx;
    __syncthreads();
    if (t < 64) {
      const float r = fmaxf(fmaxf(red[0][t], red[1][t]), fmaxf(red[2][t], red[3][t]));
      atomicMax(&wbu[f0 + t], __float_as_uint(r));
    }
    const int nl = t >> 2, ch = t & 3;
    const uint32_t* p = (const uint32_t*)&sm[nl * 68 + ch * 16];
    uint4 o = make_uint4(p[0], p[1], p[2], p[3]);
    *(uint4*)(Bs + (size_t)(f0 + nl) * KDIM + d0 + ch * 16) = o;
  }
}

// ---------------------------------------------------------------------------
// i8 sign-GEMM, 256x256 tile, 8 waves (2x4), BK=64, 4-slot LDS ring.
// SINGLE barrier per K-iter: issue 4 gloads + all 12 ds_reads upfront, then
// counted-lgkmcnt ladder interleaving 16 mfma_i32_32x32x32_i8 (swapped
// operands, D rows = n). L2-chunked grid remap; (row>>3)&3 LDS swizzle.
// C[m][n] = 0.25 * ab[m] * (wb[n]+eps) * S + bias[n]
// ---------------------------------------------------------------------------
__global__ __launch_bounds__(512, 2) void k_gemm(const int8_t* __restrict__ As,
                                                 const int8_t* __restrict__ Bs,
                                                 const float* __restrict__ ab,
                                                 const float* __restrict__ wbf,
                                                 const float* __restrict__ bias,
                                                 float* __restrict__ out) {
  __shared__ int8_t lds[4][32768];  // ring slot: A 16KB | B 16KB
  const int t = threadIdx.x;
  const int lane = t & 63, wid = t >> 6;
  // L2-chunked remap: each XCD owns 8 bm panels; iterate bn in chunks of 8 so
  // the concurrent working set stays mostly L2-resident. (R5: FETCH 543->197MB)
  const int bid = blockIdx.x;
  const int xcd = bid & 7;
  const int local = bid >> 3;            // 0..255 per XCD
  const int bnin = local & 7;
  const int bml = (local >> 3) & 7;
  const int bnc = local >> 6;            // 0..3
  const int bm = xcd * 8 + bml;          // 0..63
  const int bn = bnc * 8 + bnin;         // 0..31
  const size_t m0 = (size_t)bm * BM, n0 = (size_t)bn * BN;
  const int wr = wid >> 2, wc = wid & 3;

  // staging: LDS dest linear (row = chunkbase + lane>>2, phys slot = lane&3);
  // source slot = (lane&3) ^ xs(row), xs(row) = (row>>3)&3.
  const int srow = lane >> 2;
  const int sl0 = (lane & 3) ^ ((lane >> 5) & 1);
  const int sl1 = sl0 ^ 2;
  const int8_t* gA0 = As + (m0 + (size_t)(wid * 32 + srow)) * KDIM + sl0 * 16;
  const int8_t* gA1 = As + (m0 + (size_t)(wid * 32 + 16 + srow)) * KDIM + sl1 * 16;
  const int8_t* gB0 = Bs + (n0 + (size_t)(wid * 32 + srow)) * KDIM + sl0 * 16;
  const int8_t* gB1 = Bs + (n0 + (size_t)(wid * 32 + 16 + srow)) * KDIM + sl1 * 16;

  // 32x32x32 fragment reads: row = l31 (+32i), logical k-slot = phase*2 + h,
  // phys = logical ^ ((row>>3)&3).
  const int l31 = lane & 31, h = lane >> 5;
  const int xs = (l31 >> 3) & 3;
  const int ph0 = h ^ xs, ph1 = ph0 ^ 2;
  const int aoff0 = (wr * 128 + l31) * 64 + ph0 * 16;
  const int aoff1 = (wr * 128 + l31) * 64 + ph1 * 16;
  const int boff0 = 16384 + (wc * 64 + l31) * 64 + ph0 * 16;
  const int boff1 = 16384 + (wc * 64 + l31) * 64 + ph1 * 16;

  i32x16 acc[4][2];
#pragma unroll
  for (int i = 0; i < 4; ++i)
#pragma unroll
    for (int j = 0; j < 2; ++j) acc[i][j] = (i32x16){0};

#define ISSUE_A(u)                                      \
  do {                                                  \
    int8_t* dA = &lds[(u) & 3][wid * 2048];             \
    gload_lds16(gA0 + (size_t)(u) * BK, dA);            \
    gload_lds16(gA1 + (size_t)(u) * BK, dA + 1024);     \
  } while (0)
#define ISSUE_B(u)                                      \
  do {                                                  \
    int8_t* dB = &lds[(u) & 3][16384 + wid * 2048];     \
    gload_lds16(gB0 + (size_t)(u) * BK, dB);            \
    gload_lds16(gB1 + (size_t)(u) * BK, dB + 1024);     \
  } while (0)

#define DSR(dst, ptr, OFF) \
  asm volatile("ds_read_b128 %0, %1 offset:" #OFF : "=v"(dst) : "v"(ptr))

// swapped operands: D rows = n (b-frag first), cols = m
#define MP(I, B0, B1, AF)                                                         \
  acc[I][0] = __builtin_amdgcn_mfma_i32_32x32x32_i8(B0, AF, acc[I][0], 0, 0, 0);  \
  acc[I][1] = __builtin_amdgcn_mfma_i32_32x32x32_i8(B1, AF, acc[I][1], 0, 0, 0);

#define LGK(N)                                              \
  asm volatile("s_waitcnt lgkmcnt(" #N ")" ::: "memory");   \
  __builtin_amdgcn_sched_barrier(0);

#define ITER(TT, DOISSUE, WAIT_TAIL)                                          \
  {                                                                           \
    const int8_t* sb = &lds[(TT) & 3][0];                                     \
    lds_cptr pA0 = (lds_cptr)(sb + aoff0);                                    \
    lds_cptr pA1 = (lds_cptr)(sb + aoff1);                                    \
    lds_cptr pB0 = (lds_cptr)(sb + boff0);                                    \
    lds_cptr pB1 = (lds_cptr)(sb + boff1);                                    \
    i32x4 a0, a1, a2, a3, a4, a5, a6, a7, b0, b1, b2, b3;                     \
    if (DOISSUE) { ISSUE_A((TT) + 3); ISSUE_B((TT) + 3); }                    \
    DSR(a0, pA0, 0); DSR(b0, pB0, 0); DSR(b1, pB0, 2048);                     \
    DSR(a1, pA0, 2048); DSR(a2, pA0, 4096); DSR(a3, pA0, 6144);               \
    DSR(a4, pA1, 0); DSR(b2, pB1, 0); DSR(b3, pB1, 2048);                     \
    DSR(a5, pA1, 2048); DSR(a6, pA1, 4096); DSR(a7, pA1, 6144);               \
    LGK(9); __builtin_amdgcn_s_setprio(1); MP(0, b0, b1, a0);                 \
    LGK(8); MP(1, b0, b1, a1);                                                \
    LGK(7); MP(2, b0, b1, a2);                                                \
    LGK(6); MP(3, b0, b1, a3);                                                \
    LGK(3); MP(0, b2, b3, a4);                                                \
    LGK(2); MP(1, b2, b3, a5);                                                \
    LGK(1); MP(2, b2, b3, a6);                                                \
    LGK(0); MP(3, b2, b3, a7);                                                \
    __builtin_amdgcn_s_setprio(0);                                            \
    asm volatile(WAIT_TAIL ::: "memory");                                     \
    __builtin_amdgcn_s_barrier();                                             \
  }

  // prologue: stage tiles 0,1,2 into ring slots 0,1,2
  ISSUE_A(0); ISSUE_B(0);
  ISSUE_A(1); ISSUE_B(1);
  ISSUE_A(2); ISSUE_B(2);
  asm volatile("s_waitcnt vmcnt(8)" ::: "memory");  // tile 0 landed
  __builtin_amdgcn_s_barrier();

#pragma unroll 2
  for (int tt = 0; tt < 28; ++tt) ITER(tt, true, "s_waitcnt vmcnt(8)");
  ITER(28, true, "s_waitcnt vmcnt(8)");   // issues tile 31
  ITER(29, false, "s_waitcnt vmcnt(4)");
  ITER(30, false, "s_waitcnt vmcnt(0)");
  ITER(31, false, "s_nop 0");

  // epilogue: 32x32 C-map (swapped): m = col = l31, n = (reg&3)+8*(reg>>2)+4*h
  // -> reg-quad q gives 4 consecutive n at q*8 + 4h. Plain cached f32x4 stores.
#pragma unroll
  for (int i = 0; i < 4; ++i) {
    const size_t m = m0 + wr * 128 + i * 32 + l31;
    const float av = 0.25f * ab[m];
    float* orow = out + m * NDIM;
#pragma unroll
    for (int j = 0; j < 2; ++j) {
#pragma unroll
      for (int q = 0; q < 4; ++q) {
        const size_t nb = n0 + wc * 64 + j * 32 + q * 8 + h * 4;
        const f32x4 wv = *(const f32x4*)&wbf[nb];
        const f32x4 bv = *(const f32x4*)&bias[nb];
        f32x4 o;
        o[0] = av * ((wv[0] + EPS32) * (float)acc[i][j][q * 4 + 0]) + bv[0];
        o[1] = av * ((wv[1] + EPS32) * (float)acc[i][j][q * 4 + 1]) + bv[1];
        o[2] = av * ((wv[2] + EPS32) * (float)acc[i][j][q * 4 + 2]) + bv[2];
        o[3] = av * ((wv[3] + EPS32) * (float)acc[i][j][q * 4 + 3]) + bv[3];
        *(f32x4*)(orow + nb) = o;
      }
    }
  }
#undef ITER
#undef LGK
#undef MP
#undef DSR
#undef ISSUE_A
#undef ISSUE_B
}

extern "C" void kernel_launch(void* const* d_in, const int* in_sizes, int n_in,
                              void* d_out, int out_size, void* d_ws, size_t ws_size,
                              hipStream_t stream) {
  const float* x = (const float*)d_in[0];     // (4, 4096, 2048)
  const float* W = (const float*)d_in[1];     // (2048, 8192)
  const float* bias = (const float*)d_in[2];  // (8192,)
  float* out = (float*)d_out;

  char* ws = (char*)d_ws;
  int8_t* As = (int8_t*)ws;                                     // 32 MiB
  int8_t* Bs = (int8_t*)(ws + (size_t)(32u << 20));             // 16 MiB
  float* ab = (float*)(ws + (size_t)(48u << 20));               // 64 KiB
  float* wb = (float*)(ws + (size_t)(48u << 20) + (1u << 16));  // 32 KiB

  (void)hipMemsetAsync(wb, 0, NDIM * sizeof(float), stream);
  k_pack<<<MDIM + (KDIM / 64) * (NDIM / 64), 256, 0, stream>>>(x, W, As, Bs, ab,
                                                               (unsigned int*)wb);
  k_gemm<<<(MDIM / BM) * (NDIM / BN), 512, 0, stream>>>(As, Bs, ab, wb, bias, out);
}

// Round 8
// 418.999 us; speedup vs baseline: 1.0348x; 1.0348x over previous
//
#include <hip/hip_runtime.h>
#include <stdint.h>

#define MDIM 16384
#define NDIM 8192
#define KDIM 2048
#define EPS32 1.1920928955078125e-07f
#define BM 256
#define BN 256
#define BK 128

using i32x4 = __attribute__((ext_vector_type(4))) int;
using i32x16 = __attribute__((ext_vector_type(16))) int;
using f32x4 = __attribute__((ext_vector_type(4))) float;
typedef __attribute__((address_space(3))) const int8_t* lds_cptr;

__device__ __forceinline__ void gload_lds16(const void* g, void* l) {
  __builtin_amdgcn_global_load_lds(
      (const __attribute__((address_space(1))) void*)g,
      (__attribute__((address_space(3))) void*)l,
      16, 0, 0);
}

__device__ __forceinline__ uint32_t sgnb(float v) { return (v < 0.f) ? 0xFFu : 0x01u; }

// ---------------------------------------------------------------------------
// Fused pack: blocks [0,MDIM) pack A rows + ab[m]; blocks [MDIM, MDIM+2048)
// pack B transposed tiles + atomicMax column bound.
// ---------------------------------------------------------------------------
__global__ __launch_bounds__(256) void k_pack(const float* __restrict__ x,
                                              const float* __restrict__ W,
                                              int8_t* __restrict__ As,
                                              int8_t* __restrict__ Bs,
                                              float* __restrict__ ab,
                                              unsigned int* __restrict__ wbu) {
  __shared__ char sm[64 * 68];
  __shared__ float red[4][64];
  const int t = threadIdx.x;
  if (blockIdx.x < MDIM) {
    const int m = blockIdx.x;
    const float4* row = (const float4*)(x + (size_t)m * KDIM);
    const float4 v0 = row[2 * t];
    const float4 v1 = row[2 * t + 1];
    const uint32_t p0 = sgnb(v0.x) | (sgnb(v0.y) << 8) | (sgnb(v0.z) << 16) | (sgnb(v0.w) << 24);
    const uint32_t p1 = sgnb(v1.x) | (sgnb(v1.y) << 8) | (sgnb(v1.z) << 16) | (sgnb(v1.w) << 24);
    ((uint2*)(As + (size_t)m * KDIM))[t] = make_uint2(p0, p1);
    float mx = fmaxf(fmaxf(fabsf(v0.x), fabsf(v0.y)), fmaxf(fabsf(v0.z), fabsf(v0.w)));
    mx = fmaxf(mx, fmaxf(fmaxf(fabsf(v1.x), fabsf(v1.y)), fmaxf(fabsf(v1.w), fabsf(v1.z))));
#pragma unroll
    for (int o = 32; o > 0; o >>= 1) mx = fmaxf(mx, __shfl_xor(mx, o, 64));
    if ((t & 63) == 0) red[0][t >> 6] = mx;
    __syncthreads();
    if (t == 0)
      ab[m] = fmaxf(fmaxf(red[0][0], red[0][1]), fmaxf(red[0][2], red[0][3])) + EPS32;
  } else {
    const int bid = blockIdx.x - MDIM;
    const int bd = bid & 31;  // 2048/64 d-tiles
    const int bf = bid >> 5;  // 8192/64 f-tiles
    const int d0 = bd * 64, f0 = bf * 64;
    const int fl = t & 63, dq = t >> 6;
    float mx = 0.f;
#pragma unroll
    for (int i = 0; i < 16; ++i) {
      const int dl = i * 4 + dq;
      const float v = W[(size_t)(d0 + dl) * NDIM + f0 + fl];
      sm[fl * 68 + dl] = (v < 0.f) ? (char)-1 : (char)1;
      mx = fmaxf(mx, fabsf(v));
    }
    red[dq][fl] = mx;
    __syncthreads();
    if (t < 64) {
      const float r = fmaxf(fmaxf(red[0][t], red[1][t]), fmaxf(red[2][t], red[3][t]));
      atomicMax(&wbu[f0 + t], __float_as_uint(r));
    }
    const int nl = t >> 2, ch = t & 3;
    const uint32_t* p = (const uint32_t*)&sm[nl * 68 + ch * 16];
    uint4 o = make_uint4(p[0], p[1], p[2], p[3]);
    *(uint4*)(Bs + (size_t)(f0 + nl) * KDIM + d0 + ch * 16) = o;
  }
}

// ---------------------------------------------------------------------------
// i8 sign-GEMM, 256x256 tile, 8 waves (2x4), BK=128 (full-cache-line rows),
// 2-slot LDS ring, prefetch distance 1 (per-wave vmcnt(0) hidden under iter),
// counted-lgkmcnt ladder, mfma_i32_32x32x32_i8 swapped operands (D rows = n).
// LDS swizzle: phys16Bslot = logical ^ (row&7), both sides. L2-chunked remap.
// C[m][n] = 0.25 * ab[m] * (wb[n]+eps) * S + bias[n]
// ---------------------------------------------------------------------------
__global__ __launch_bounds__(512, 2) void k_gemm(const int8_t* __restrict__ As,
                                                 const int8_t* __restrict__ Bs,
                                                 const float* __restrict__ ab,
                                                 const float* __restrict__ wbf,
                                                 const float* __restrict__ bias,
                                                 float* __restrict__ out) {
  __shared__ int8_t lds[2][65536];  // ring slot: A 32KB | B 32KB
  const int t = threadIdx.x;
  const int lane = t & 63, wid = t >> 6;
  // L2-chunked remap (R5: FETCH 543->197MB)
  const int bid = blockIdx.x;
  const int xcd = bid & 7;
  const int local = bid >> 3;
  const int bnin = local & 7;
  const int bml = (local >> 3) & 7;
  const int bnc = local >> 6;
  const int bm = xcd * 8 + bml;
  const int bn = bnc * 8 + bnin;
  const size_t m0 = (size_t)bm * BM, n0 = (size_t)bn * BN;
  const int wr = wid >> 2, wc = wid & 3;

  // staging: each instr covers 8 rows x 128B (one full cache line per row).
  // dest linear: lane L -> row base+L>>3, phys slot L&7.
  // source slot = (L&7) ^ (L>>3)  (inverse swizzle so read-side XOR cancels).
  const int r8 = lane >> 3;
  const int ss = ((lane & 7) ^ r8) * 16;
  const int8_t* gA[4];
  const int8_t* gB[4];
#pragma unroll
  for (int c = 0; c < 4; ++c) {
    gA[c] = As + (m0 + (size_t)(wid * 32 + c * 8 + r8)) * KDIM + ss;
    gB[c] = Bs + (n0 + (size_t)(wid * 32 + c * 8 + r8)) * KDIM + ss;
  }

  // fragment reads: row = (tile_off + l31), logical slot = kk*2 + h,
  // phys = logical ^ (row&7) = logical ^ (l31&7). imm offset mi*4096 (32 rows).
  const int l31 = lane & 31, h = lane >> 5;
  const int x7 = l31 & 7;
  int offA[4], offB[4];
#pragma unroll
  for (int kk = 0; kk < 4; ++kk) {
    const int ph = ((kk * 2 + h) ^ x7) * 16;
    offA[kk] = (wr * 128 + l31) * 128 + ph;
    offB[kk] = 32768 + (wc * 64 + l31) * 128 + ph;
  }

  i32x16 acc[4][2];
#pragma unroll
  for (int i = 0; i < 4; ++i)
#pragma unroll
    for (int j = 0; j < 2; ++j) acc[i][j] = (i32x16){0};

#define ISSUE(u)                                                     \
  do {                                                               \
    int8_t* dA = &lds[(u) & 1][wid * 4096];                          \
    int8_t* dB = &lds[(u) & 1][32768 + wid * 4096];                  \
    _Pragma("unroll") for (int c = 0; c < 4; ++c) {                  \
      gload_lds16(gA[c] + (size_t)(u) * BK, dA + c * 1024);          \
      gload_lds16(gB[c] + (size_t)(u) * BK, dB + c * 1024);          \
    }                                                                \
  } while (0)

#define DSR(dst, ptr, OFF) \
  asm volatile("ds_read_b128 %0, %1 offset:" #OFF : "=v"(dst) : "v"(ptr))

// swapped operands: D rows = n (b-frag first), cols = m
#define MK(B0, B1, A0, A1, A2, A3)                                                \
  acc[0][0] = __builtin_amdgcn_mfma_i32_32x32x32_i8(B0, A0, acc[0][0], 0, 0, 0);  \
  acc[0][1] = __builtin_amdgcn_mfma_i32_32x32x32_i8(B1, A0, acc[0][1], 0, 0, 0);  \
  acc[1][0] = __builtin_amdgcn_mfma_i32_32x32x32_i8(B0, A1, acc[1][0], 0, 0, 0);  \
  acc[1][1] = __builtin_amdgcn_mfma_i32_32x32x32_i8(B1, A1, acc[1][1], 0, 0, 0);  \
  acc[2][0] = __builtin_amdgcn_mfma_i32_32x32x32_i8(B0, A2, acc[2][0], 0, 0, 0);  \
  acc[2][1] = __builtin_amdgcn_mfma_i32_32x32x32_i8(B1, A2, acc[2][1], 0, 0, 0);  \
  acc[3][0] = __builtin_amdgcn_mfma_i32_32x32x32_i8(B0, A3, acc[3][0], 0, 0, 0);  \
  acc[3][1] = __builtin_amdgcn_mfma_i32_32x32x32_i8(B1, A3, acc[3][1], 0, 0, 0);

#define LGK(N)                                              \
  asm volatile("s_waitcnt lgkmcnt(" #N ")" ::: "memory");   \
  __builtin_amdgcn_sched_barrier(0);

#define RD6(K, AA0, AA1, AA2, AA3, BB0, BB1)                                  \
  {                                                                           \
    lds_cptr qa = (lds_cptr)(sb + offA[K]);                                   \
    lds_cptr qb = (lds_cptr)(sb + offB[K]);                                   \
    DSR(AA0, qa, 0); DSR(AA1, qa, 4096); DSR(AA2, qa, 8192);                  \
    DSR(AA3, qa, 12288); DSR(BB0, qb, 0); DSR(BB1, qb, 4096);                 \
  }

#define ITER(TT, DOISSUE, WAIT_TAIL)                                          \
  {                                                                           \
    const int8_t* sb = &lds[(TT) & 1][0];                                     \
    i32x4 a0, a1, a2, a3, a4, a5, a6, a7, b0, b1, b2, b3;                     \
    if (DOISSUE) ISSUE((TT) + 1);                                             \
    RD6(0, a0, a1, a2, a3, b0, b1);                                           \
    RD6(1, a4, a5, a6, a7, b2, b3);                                           \
    LGK(6); __builtin_amdgcn_s_setprio(1); MK(b0, b1, a0, a1, a2, a3);        \
    RD6(2, a0, a1, a2, a3, b0, b1);                                           \
    LGK(6); MK(b2, b3, a4, a5, a6, a7);                                       \
    RD6(3, a4, a5, a6, a7, b2, b3);                                           \
    LGK(6); MK(b0, b1, a0, a1, a2, a3);                                       \
    LGK(0); MK(b2, b3, a4, a5, a6, a7);                                       \
    __builtin_amdgcn_s_setprio(0);                                            \
    asm volatile(WAIT_TAIL ::: "memory");                                     \
    __builtin_amdgcn_s_barrier();                                             \
  }

  // prologue: stage tile 0 into slot 0
  ISSUE(0);
  asm volatile("s_waitcnt vmcnt(0)" ::: "memory");
  __builtin_amdgcn_s_barrier();

#pragma unroll 3
  for (int tt = 0; tt < 15; ++tt) ITER(tt, true, "s_waitcnt vmcnt(0)");
  ITER(15, false, "s_nop 0");

  // epilogue: 32x32 C-map (swapped): m = col = l31, n = (reg&3)+8*(reg>>2)+4*h
#pragma unroll
  for (int i = 0; i < 4; ++i) {
    const size_t m = m0 + wr * 128 + i * 32 + l31;
    const float av = 0.25f * ab[m];
    float* orow = out + m * NDIM;
#pragma unroll
    for (int j = 0; j < 2; ++j) {
#pragma unroll
      for (int q = 0; q < 4; ++q) {
        const size_t nb = n0 + wc * 64 + j * 32 + q * 8 + h * 4;
        const f32x4 wv = *(const f32x4*)&wbf[nb];
        const f32x4 bv = *(const f32x4*)&bias[nb];
        f32x4 o;
        o[0] = av * ((wv[0] + EPS32) * (float)acc[i][j][q * 4 + 0]) + bv[0];
        o[1] = av * ((wv[1] + EPS32) * (float)acc[i][j][q * 4 + 1]) + bv[1];
        o[2] = av * ((wv[2] + EPS32) * (float)acc[i][j][q * 4 + 2]) + bv[2];
        o[3] = av * ((wv[3] + EPS32) * (float)acc[i][j][q * 4 + 3]) + bv[3];
        *(f32x4*)(orow + nb) = o;
      }
    }
  }
#undef ITER
#undef RD6
#undef LGK
#undef MK
#undef DSR
#undef ISSUE
}

extern "C" void kernel_launch(void* const* d_in, const int* in_sizes, int n_in,
                              void* d_out, int out_size, void* d_ws, size_t ws_size,
                              hipStream_t stream) {
  const float* x = (const float*)d_in[0];     // (4, 4096, 2048)
  const float* W = (const float*)d_in[1];     // (2048, 8192)
  const float* bias = (const float*)d_in[2];  // (8192,)
  float* out = (float*)d_out;

  char* ws = (char*)d_ws;
  int8_t* As = (int8_t*)ws;                                     // 32 MiB
  int8_t* Bs = (int8_t*)(ws + (size_t)(32u << 20));             // 16 MiB
  float* ab = (float*)(ws + (size_t)(48u << 20));               // 64 KiB
  float* wb = (float*)(ws + (size_t)(48u << 20) + (1u << 16));  // 32 KiB

  (void)hipMemsetAsync(wb, 0, NDIM * sizeof(float), stream);
  k_pack<<<MDIM + (KDIM / 64) * (NDIM / 64), 256, 0, stream>>>(x, W, As, Bs, ab,
                                                               (unsigned int*)wb);
  k_gemm<<<(MDIM / BM) * (NDIM / BN), 512, 0, stream>>>(As, Bs, ab, wb, bias, out);
}